// Round 11
// baseline (98.286 us; speedup 1.0000x reference)
//
#include <hip/hip_runtime.h>

// Adaptive downsampler: B=8, C=3, 1024x1024 -> 512x512, K2=9 taps,
// bilinear gather from reflect-padded (pad=1) image, weighted by kernels.
// R11 = R10 (72.0us: LDS window staging + lean fast path + exact fallback,
//       27-wide nt preload, XCD slab swizzle, plain stores)
//       with 1024-thread blocks / 64x16 patch / 46x144x3 window (79.5 KB):
//       exactly 2 blocks/CU -> 32 waves/CU (100% occupancy cap) to overlap
//       the VALU (39%) and LDS-conflict (~27%) pipes.
constexpr int B_  = 8;
constexpr int C_  = 3;
constexpr int H_  = 1024;
constexpr int W_  = 1024;
constexpr int HO_ = 512;
constexpr int WO_ = 512;
constexpr int K2_ = 9;
constexpr int KS_ = 3;
constexpr int HP_ = H_ + 2;   // padded height (pad=1)
constexpr int WP_ = W_ + 2;   // padded width
constexpr int TPB_  = 1024;
constexpr int NBLK_ = (B_ * HO_ * WO_) / TPB_;  // 2048 blocks
constexpr int NXCD_ = 8;

// LDS window: WY_ rows x WX_ cols x 3 channels
constexpr int WY_  = 46;
constexpr int WX_  = 144;
constexpr int WX4_ = WX_ / 4;              // 36
constexpr int WCH_ = WY_ * WX_;            // 6624 floats per channel
constexpr int NF4_ = 3 * WY_ * WX4_;       // 4968 float4 to stage

__device__ __forceinline__ float2 ld2(const float* p) {
    float2 r;
    __builtin_memcpy(&r, p, sizeof(float2));   // global_load_dwordx2
    return r;
}

__global__ __launch_bounds__(TPB_) void ds_kernel(
    const float* __restrict__ img,
    const float* __restrict__ kern,
    const float* __restrict__ offh,
    const float* __restrict__ offv,
    const float* __restrict__ unit_p,
    float* __restrict__ out)
{
    const int HWo = HO_ * WO_;                       // 262144
    __shared__ float sh[3 * WCH_];                   // 79488 B

    // XCD swizzle: block i runs on XCD i%8; contiguous 256-block slab
    // per XCD = one batch, oy-ordered -> image window L2-resident.
    const int wg  = blockIdx.x;
    const int nid = (wg & (NXCD_ - 1)) * (NBLK_ / NXCD_) + (wg >> 3);

    // 2D patch decode: nid = b*256 + oyt*8 + oxt
    const int b   = nid >> 8;
    const int q   = nid & 255;
    const int oyt = q >> 3;             // 0..31: 16-row oy group
    const int oxt = q & 7;              // 0..7:  64-px ox chunk
    const int wv  = threadIdx.x >> 6;   // 0..15
    const int ln  = threadIdx.x & 63;
    const int oy  = oyt * 16 + wv;
    const int ox  = oxt * 64 + ln;

    const float unit = unit_p[0];
    const float* imgb = img + (size_t)b * (C_ * H_ * W_);
    const int kbase = b * (K2_ * HWo) + oy * WO_ + ox;   // < 2^25

    // Window origin (orig-image coords), x 4-aligned for float4 staging.
    int wxlo = 128 * oxt - 8;
    wxlo = wxlo < 0 ? 0 : (wxlo > W_ - WX_ ? W_ - WX_ : wxlo);   // 0..880, %4==0
    int wylo = 32 * oyt - 6;
    wylo = wylo < 0 ? 0 : (wylo > H_ - WY_ ? H_ - WY_ : wylo);   // 0..978

    // Phase 1: all 27 stream loads in flight (read-once -> nontemporal).
    float wk[K2_], oh[K2_], ov[K2_];
#pragma unroll
    for (int k = 0; k < K2_; ++k) {
        wk[k] = __builtin_nontemporal_load(kern + kbase + k * HWo);
        oh[k] = __builtin_nontemporal_load(offh + kbase + k * HWo);
        ov[k] = __builtin_nontemporal_load(offv + kbase + k * HWo);
    }

    // Phase 2: stage the image window into LDS (coalesced float4).
#pragma unroll
    for (int i = 0; i < 5; ++i) {
        const int it = threadIdx.x + i * TPB_;
        if (it < NF4_) {
            const int ch  = it / (WY_ * WX4_);
            const int rem = it - ch * (WY_ * WX4_);
            const int row = rem / WX4_;
            const int c4  = rem - row * WX4_;
            const float4 v = ((const float4*)(imgb + ch * (H_ * W_)
                                + (wylo + row) * W_ + wxlo))[c4];
            ((float4*)(sh + ch * WCH_ + row * WX_))[c4] = v;
        }
    }
    __syncthreads();

    // (ox+0.5)/WO*W - 0.5 == 2*ox + 0.5  (exact in fp32; W/WO = 2)
    const float cx = 2.0f * (float)ox + 0.5f;
    const float cy = 2.0f * (float)oy + 0.5f;

    float acc0 = 0.0f, acc1 = 0.0f, acc2 = 0.0f;

    // Phase 3: taps, fully unrolled; lean LDS fast path + exact fallback.
#pragma unroll
    for (int k = 0; k < K2_; ++k) {
        const float px = cx + (float)(k % KS_) + oh[k] * unit;
        const float py = cy + (float)(k / KS_) + ov[k] * unit;

        const float fx = floorf(px);
        const float fy = floorf(py);
        const float a  = px - fx;   // alpha
        const float bt = py - fy;   // beta

        // raw corner (orig coords); if in window, clip is inactive and
        // reflect is identity (window subset of [0,W-1]x[0,H-1]).
        const int x0 = (int)fx - 1;
        const int y0 = (int)fy - 1;

        const float wt = wk[k] * (1.0f - bt);
        const float wb = wk[k] * bt;

        const bool inwin = (x0 >= wxlo) & (x0 <= wxlo + WX_ - 2)
                         & (y0 >= wylo) & (y0 <= wylo + WY_ - 2);

        if (inwin) {
            const float ax0 = 1.0f - a;
            const float ax1 = a;
            const int i_t = (y0 - wylo) * WX_ + (x0 - wxlo);
            const int i_b = i_t + WX_;
            {
                const float* shc = sh;
                acc0 = fmaf(wt, fmaf(ax0, shc[i_t], ax1 * shc[i_t + 1]),
                       fmaf(wb, fmaf(ax0, shc[i_b], ax1 * shc[i_b + 1]), acc0));
            }
            {
                const float* shc = sh + WCH_;
                acc1 = fmaf(wt, fmaf(ax0, shc[i_t], ax1 * shc[i_t + 1]),
                       fmaf(wb, fmaf(ax0, shc[i_b], ax1 * shc[i_b + 1]), acc1));
            }
            {
                const float* shc = sh + 2 * WCH_;
                acc2 = fmaf(wt, fmaf(ax0, shc[i_t], ax1 * shc[i_t + 1]),
                       fmaf(wb, fmaf(ax0, shc[i_b], ax1 * shc[i_b + 1]), acc2));
            }
        } else {
            // exact reference semantics: clip in padded coords + reflect
            int xL = (int)fx; xL = xL < 0 ? 0 : (xL > WP_ - 1 ? WP_ - 1 : xL);
            int xR = xL + 1;  xR = xR > WP_ - 1 ? WP_ - 1 : xR;
            int yT = (int)fy; yT = yT < 0 ? 0 : (yT > HP_ - 1 ? HP_ - 1 : yT);
            int yB = yT + 1;  yB = yB > HP_ - 1 ? HP_ - 1 : yB;

            int xl = xL - 1; xl = (xl < 0) ? -xl : (xl >= W_ ? 2 * W_ - 2 - xl : xl);
            int xr = xR - 1; xr = (xr < 0) ? -xr : (xr >= W_ ? 2 * W_ - 2 - xr : xr);
            int yt = yT - 1; yt = (yt < 0) ? -yt : (yt >= H_ ? 2 * H_ - 2 - yt : yt);
            int yb = yB - 1; yb = (yb < 0) ? -yb : (yb >= H_ ? 2 * H_ - 2 - yb : yb);

            const int base = xl < xr ? xl : xr;
            const float ax0 = ((xl == base) ? (1.0f - a) : 0.0f)
                            + ((xr == base) ? a : 0.0f);
            const float ax1 = 1.0f - ax0;

            const int r0 = yt * W_ + base;
            const int r1 = yb * W_ + base;
            {
                const float2 v = ld2(imgb + r0);
                const float2 u = ld2(imgb + r1);
                acc0 = fmaf(wt, fmaf(ax0, v.x, ax1 * v.y),
                       fmaf(wb, fmaf(ax0, u.x, ax1 * u.y), acc0));
            }
            {
                const float2 v = ld2(imgb + H_ * W_ + r0);
                const float2 u = ld2(imgb + H_ * W_ + r1);
                acc1 = fmaf(wt, fmaf(ax0, v.x, ax1 * v.y),
                       fmaf(wb, fmaf(ax0, u.x, ax1 * u.y), acc1));
            }
            {
                const float2 v = ld2(imgb + 2 * H_ * W_ + r0);
                const float2 u = ld2(imgb + 2 * H_ * W_ + r1);
                acc2 = fmaf(wt, fmaf(ax0, v.x, ax1 * v.y),
                       fmaf(wb, fmaf(ax0, u.x, ax1 * u.y), acc2));
            }
        }
    }

    const int obase = b * (C_ * HWo) + oy * WO_ + ox;
    out[obase]           = acc0;
    out[obase + HWo]     = acc1;
    out[obase + 2 * HWo] = acc2;
}

extern "C" void kernel_launch(void* const* d_in, const int* in_sizes, int n_in,
                              void* d_out, int out_size, void* d_ws, size_t ws_size,
                              hipStream_t stream) {
    const float* img  = (const float*)d_in[0];
    const float* kern = (const float*)d_in[1];
    const float* offh = (const float*)d_in[2];
    const float* offv = (const float*)d_in[3];
    const float* unit = (const float*)d_in[4];
    float* out = (float*)d_out;

    ds_kernel<<<NBLK_, TPB_, 0, stream>>>(img, kern, offh, offv, unit, out);
}

// Round 12
// 72.476 us; speedup vs baseline: 1.3561x; 1.3561x over previous
//
#include <hip/hip_runtime.h>

// Adaptive downsampler: B=8, C=3, 1024x1024 -> 512x512, K2=9 taps,
// bilinear gather from reflect-padded (pad=1) image, weighted by kernels.
// R12 = R10 (72.0us best: 512-thr/64x8 patch, 30x144x3 LDS window, lean
//       fast path + exact fallback, 27-wide nt preload, XCD slab swizzle)
//       + even/odd column split in LDS: bilinear pair (x0,x0+1) = one even
//       + one odd element -> lane index stride-1 per array -> bank-conflict
//       free reads (was 4-way at stride-2, 1.475e7 conflict cycles).
constexpr int B_  = 8;
constexpr int C_  = 3;
constexpr int H_  = 1024;
constexpr int W_  = 1024;
constexpr int HO_ = 512;
constexpr int WO_ = 512;
constexpr int K2_ = 9;
constexpr int KS_ = 3;
constexpr int HP_ = H_ + 2;   // padded height (pad=1)
constexpr int WP_ = W_ + 2;   // padded width
constexpr int TPB_  = 512;
constexpr int NBLK_ = (B_ * HO_ * WO_) / TPB_;  // 4096 blocks
constexpr int NXCD_ = 8;

// LDS window: WY_ rows x WX_ cols x 3 channels, split into even/odd columns.
constexpr int WY_   = 30;
constexpr int WX_   = 144;
constexpr int WXH_  = WX_ / 2;             // 72 cols per half
constexpr int WX4_  = WX_ / 4;             // 36 float4 per row
constexpr int WCH2_ = WY_ * WXH_;          // 2160 floats per (ch, half)
constexpr int NF4_  = 3 * WY_ * WX4_;      // 3240 float4 to stage
// layout: sh[0 .. 3*WCH2_) = even cols (ch-major), sh[3*WCH2_ ..) = odd cols

__device__ __forceinline__ float2 ld2(const float* p) {
    float2 r;
    __builtin_memcpy(&r, p, sizeof(float2));   // global_load_dwordx2
    return r;
}

__global__ __launch_bounds__(TPB_) void ds_kernel(
    const float* __restrict__ img,
    const float* __restrict__ kern,
    const float* __restrict__ offh,
    const float* __restrict__ offv,
    const float* __restrict__ unit_p,
    float* __restrict__ out)
{
    const int HWo = HO_ * WO_;                       // 262144
    __shared__ float sh[6 * WCH2_];                  // 51840 B

    // XCD swizzle: block i runs on XCD i%8; contiguous 512-block slab
    // per XCD = one batch, oy-ordered -> image window L2-resident.
    const int wg  = blockIdx.x;
    const int nid = (wg & (NXCD_ - 1)) * (NBLK_ / NXCD_) + (wg >> 3);

    // 2D patch decode: nid = b*512 + oyt*8 + oxt
    const int b   = nid >> 9;
    const int q   = nid & 511;
    const int oyt = q >> 3;             // 0..63: 8-row oy group
    const int oxt = q & 7;              // 0..7:  64-px ox chunk
    const int wv  = threadIdx.x >> 6;   // 0..7
    const int ln  = threadIdx.x & 63;
    const int oy  = oyt * 8 + wv;
    const int ox  = oxt * 64 + ln;

    const float unit = unit_p[0];
    const float* imgb = img + (size_t)b * (C_ * H_ * W_);
    const int kbase = b * (K2_ * HWo) + oy * WO_ + ox;   // < 2^25

    // Window origin (orig-image coords), x 4-aligned for float4 staging.
    int wxlo = 128 * oxt - 8;
    wxlo = wxlo < 0 ? 0 : (wxlo > W_ - WX_ ? W_ - WX_ : wxlo);   // 0..880, %4==0
    int wylo = 16 * oyt - 7;
    wylo = wylo < 0 ? 0 : (wylo > H_ - WY_ ? H_ - WY_ : wylo);   // 0..994

    // Phase 1: all 27 stream loads in flight (read-once -> nontemporal).
    float wk[K2_], oh[K2_], ov[K2_];
#pragma unroll
    for (int k = 0; k < K2_; ++k) {
        wk[k] = __builtin_nontemporal_load(kern + kbase + k * HWo);
        oh[k] = __builtin_nontemporal_load(offh + kbase + k * HWo);
        ov[k] = __builtin_nontemporal_load(offv + kbase + k * HWo);
    }

    // Phase 2: stage the image window into LDS (coalesced float4 loads,
    // even/odd-split float2 writes: cols 4c,4c+2 -> E[2c,2c+1]; 4c+1,4c+3
    // -> O[2c,2c+1]; both 8B-aligned ds_write_b64).
#pragma unroll
    for (int i = 0; i < 7; ++i) {
        const int it = threadIdx.x + i * TPB_;
        if (it < NF4_) {
            const int ch  = it / (WY_ * WX4_);
            const int rem = it - ch * (WY_ * WX4_);
            const int row = rem / WX4_;
            const int c4  = rem - row * WX4_;
            const float4 v = ((const float4*)(imgb + ch * (H_ * W_)
                                + (wylo + row) * W_ + wxlo))[c4];
            float* eRow = sh + ch * WCH2_ + row * WXH_;
            float* oRow = eRow + 3 * WCH2_;
            ((float2*)eRow)[c4] = make_float2(v.x, v.z);
            ((float2*)oRow)[c4] = make_float2(v.y, v.w);
        }
    }
    __syncthreads();

    // (ox+0.5)/WO*W - 0.5 == 2*ox + 0.5  (exact in fp32; W/WO = 2)
    const float cx = 2.0f * (float)ox + 0.5f;
    const float cy = 2.0f * (float)oy + 0.5f;

    float acc0 = 0.0f, acc1 = 0.0f, acc2 = 0.0f;

    // Phase 3: taps, fully unrolled; lean LDS fast path + exact fallback.
#pragma unroll
    for (int k = 0; k < K2_; ++k) {
        const float px = cx + (float)(k % KS_) + oh[k] * unit;
        const float py = cy + (float)(k / KS_) + ov[k] * unit;

        const float fx = floorf(px);
        const float fy = floorf(py);
        const float a  = px - fx;   // alpha
        const float bt = py - fy;   // beta

        // raw corner (orig coords); if in window, clip is inactive and
        // reflect is identity (window subset of [0,W-1]x[0,H-1]).
        const int x0 = (int)fx - 1;
        const int y0 = (int)fy - 1;

        const float wt = wk[k] * (1.0f - bt);
        const float wb = wk[k] * bt;

        const bool inwin = (x0 >= wxlo) & (x0 <= wxlo + WX_ - 2)
                         & (y0 >= wylo) & (y0 <= wylo + WY_ - 2);

        if (inwin) {
            const int xr = x0 - wxlo;        // 0..142
            const int p  = xr & 1;
            const int h  = xr >> 1;          // 0..71
            // (x0,x0+1) -> E[h+p], O[h]; alpha-weights swap with parity:
            const float axE = p ? a : 1.0f - a;
            const float axO = p ? 1.0f - a : a;
            const int rT = (y0 - wylo) * WXH_ + h;
            const int iE = rT + p;
            const int iO = rT;
            {
                const float* eC = sh;
                const float* oC = sh + 3 * WCH2_;
                acc0 = fmaf(wt, fmaf(axE, eC[iE], axO * oC[iO]),
                       fmaf(wb, fmaf(axE, eC[iE + WXH_], axO * oC[iO + WXH_]), acc0));
            }
            {
                const float* eC = sh + WCH2_;
                const float* oC = sh + 4 * WCH2_;
                acc1 = fmaf(wt, fmaf(axE, eC[iE], axO * oC[iO]),
                       fmaf(wb, fmaf(axE, eC[iE + WXH_], axO * oC[iO + WXH_]), acc1));
            }
            {
                const float* eC = sh + 2 * WCH2_;
                const float* oC = sh + 5 * WCH2_;
                acc2 = fmaf(wt, fmaf(axE, eC[iE], axO * oC[iO]),
                       fmaf(wb, fmaf(axE, eC[iE + WXH_], axO * oC[iO + WXH_]), acc2));
            }
        } else {
            // exact reference semantics: clip in padded coords + reflect
            int xL = (int)fx; xL = xL < 0 ? 0 : (xL > WP_ - 1 ? WP_ - 1 : xL);
            int xR = xL + 1;  xR = xR > WP_ - 1 ? WP_ - 1 : xR;
            int yT = (int)fy; yT = yT < 0 ? 0 : (yT > HP_ - 1 ? HP_ - 1 : yT);
            int yB = yT + 1;  yB = yB > HP_ - 1 ? HP_ - 1 : yB;

            int xl = xL - 1; xl = (xl < 0) ? -xl : (xl >= W_ ? 2 * W_ - 2 - xl : xl);
            int xr2 = xR - 1; xr2 = (xr2 < 0) ? -xr2 : (xr2 >= W_ ? 2 * W_ - 2 - xr2 : xr2);
            int yt = yT - 1; yt = (yt < 0) ? -yt : (yt >= H_ ? 2 * H_ - 2 - yt : yt);
            int yb = yB - 1; yb = (yb < 0) ? -yb : (yb >= H_ ? 2 * H_ - 2 - yb : yb);

            const int base = xl < xr2 ? xl : xr2;
            const float ax0 = ((xl == base) ? (1.0f - a) : 0.0f)
                            + ((xr2 == base) ? a : 0.0f);
            const float ax1 = 1.0f - ax0;

            const int r0 = yt * W_ + base;
            const int r1 = yb * W_ + base;
            {
                const float2 v = ld2(imgb + r0);
                const float2 u = ld2(imgb + r1);
                acc0 = fmaf(wt, fmaf(ax0, v.x, ax1 * v.y),
                       fmaf(wb, fmaf(ax0, u.x, ax1 * u.y), acc0));
            }
            {
                const float2 v = ld2(imgb + H_ * W_ + r0);
                const float2 u = ld2(imgb + H_ * W_ + r1);
                acc1 = fmaf(wt, fmaf(ax0, v.x, ax1 * v.y),
                       fmaf(wb, fmaf(ax0, u.x, ax1 * u.y), acc1));
            }
            {
                const float2 v = ld2(imgb + 2 * H_ * W_ + r0);
                const float2 u = ld2(imgb + 2 * H_ * W_ + r1);
                acc2 = fmaf(wt, fmaf(ax0, v.x, ax1 * v.y),
                       fmaf(wb, fmaf(ax0, u.x, ax1 * u.y), acc2));
            }
        }
    }

    const int obase = b * (C_ * HWo) + oy * WO_ + ox;
    out[obase]           = acc0;
    out[obase + HWo]     = acc1;
    out[obase + 2 * HWo] = acc2;
}

extern "C" void kernel_launch(void* const* d_in, const int* in_sizes, int n_in,
                              void* d_out, int out_size, void* d_ws, size_t ws_size,
                              hipStream_t stream) {
    const float* img  = (const float*)d_in[0];
    const float* kern = (const float*)d_in[1];
    const float* offh = (const float*)d_in[2];
    const float* offv = (const float*)d_in[3];
    const float* unit = (const float*)d_in[4];
    float* out = (float*)d_out;

    ds_kernel<<<NBLK_, TPB_, 0, stream>>>(img, kern, offh, offv, unit, out);
}